// Round 2
// baseline (420.339 us; speedup 1.0000x reference)
//
#include <hip/hip_runtime.h>
#include <cstdint>
#include <cstddef>

// Problem constants: N=4, C=D=256, H=W=64, L=4096
#define NB 4
#define CH 256
#define LL 4096

typedef unsigned short u16;
typedef unsigned int u32;
typedef unsigned char u8;
typedef __attribute__((ext_vector_type(8))) short bf16x8;
typedef __attribute__((ext_vector_type(4))) float f32x4;

#define GPTR(p) ((const __attribute__((address_space(1))) u32*)(p))
#define LPTR(p) ((__attribute__((address_space(3))) u32*)(p))

__device__ __forceinline__ float blo(u32 x) { return __uint_as_float(x << 16); }
__device__ __forceinline__ float bhi(u32 x) { return __uint_as_float(x & 0xffff0000u); }
__device__ __forceinline__ float b2f(u16 h) { return __uint_as_float(((u32)h) << 16); }
__device__ __forceinline__ u16 f2b(float f) {
    u32 u = __float_as_uint(f);
    u32 r = (u + 0x7fffu + ((u >> 16) & 1u)) >> 16;  // RNE
    return (u16)r;
}
__device__ __forceinline__ u32 pack2(float a, float b) {
    return (u32)f2b(a) | ((u32)f2b(b) << 16);
}

// ---------------------------------------------------------------------------
// Kernel 0b: cast weights to bf16 (Wb[mat][d][c]) + zero BN stats.
// ---------------------------------------------------------------------------
__global__ __launch_bounds__(256) void castw_kernel(
    const float* __restrict__ Wq, const float* __restrict__ Wk,
    const float* __restrict__ Wv, const float* __restrict__ Wo,
    u16* __restrict__ Wb, float* __restrict__ stats) {
    const int i = blockIdx.x * 256 + threadIdx.x;
    const int m = blockIdx.y;
    if (m == 0 && blockIdx.x < 2) stats[i] = 0.0f;
    const float* src = (m == 0) ? Wq : (m == 1) ? Wk : (m == 2) ? Wv : Wo;
    float4 v = ((const float4*)src)[i];
    uint2 o;
    o.x = pack2(v.x, v.y);
    o.y = pack2(v.z, v.w);
    ((uint2*)(Wb + m * 65536))[i] = o;
}

// ---------------------------------------------------------------------------
// Kernel 0c: transpose-cast x[n][c][l] f32 -> xT[n][l][c] bf16 (64x64 tiles).
// ---------------------------------------------------------------------------
__global__ __launch_bounds__(256) void tcast_kernel(
    const float* __restrict__ x, u16* __restrict__ xT) {
    const int n = blockIdx.z;
    const int c0 = blockIdx.y * 64, l0 = blockIdx.x * 64;
    __shared__ u16 t[64][72];
    const float* xs = x + (size_t)n * CH * LL;
    const int tid = threadIdx.x;
    const int lq = (tid & 15) * 4, cc = tid >> 4;
#pragma unroll
    for (int p = 0; p < 4; ++p) {
        int c = cc + p * 16;
        float4 v = *(const float4*)&xs[(size_t)(c0 + c) * LL + l0 + lq];
        t[lq + 0][c] = f2b(v.x);
        t[lq + 1][c] = f2b(v.y);
        t[lq + 2][c] = f2b(v.z);
        t[lq + 3][c] = f2b(v.w);
    }
    __syncthreads();
    u16* xo = xT + (size_t)n * LL * CH;
    const int l = tid >> 2, c8 = (tid & 3) * 16;
#pragma unroll
    for (int h = 0; h < 2; ++h) {
        uint4 vv = *(uint4*)&t[l][c8 + h * 8];
        *(uint4*)&xo[(size_t)(l0 + l) * CH + c0 + c8 + h * 8] = vv;
    }
}

// ---------------------------------------------------------------------------
// Kernel 1a: q/k projections via bf16 MFMA, output bf16. (fp8 q/k is the
// correlated-error path: R9 absmax 0.22 -- must stay bf16.)
// ---------------------------------------------------------------------------
__global__ __launch_bounds__(256, 1) void projqk_kernel(
    const u16* __restrict__ xT, const u16* __restrict__ Wb,
    u16* __restrict__ q, u16* __restrict__ k) {
    const int n = blockIdx.z;
    const int dhalf = blockIdx.y & 1, mat = blockIdx.y >> 1;
    const int l0 = blockIdx.x * 64;
    const int d0 = dhalf * 128;
    const int tid = threadIdx.x;
    const int w = tid >> 6, lane = tid & 63;
    const int lhi = lane >> 4, llo = lane & 15;

    const u16* xn = xT + (size_t)n * LL * CH;
    const u16* Wm = Wb + mat * 65536;

    bf16x8 af[8];
    const u16* abase = xn + (size_t)(l0 + w * 16 + llo) * CH + lhi * 8;
#pragma unroll
    for (int ks = 0; ks < 8; ++ks) af[ks] = *(const bf16x8*)(abase + ks * 32);

    f32x4 acc[8];
#pragma unroll
    for (int t = 0; t < 8; ++t) acc[t] = (f32x4){0.f, 0.f, 0.f, 0.f};

#pragma unroll
    for (int ks = 0; ks < 8; ++ks) {
#pragma unroll
        for (int ct = 0; ct < 8; ++ct) {
            bf16x8 bf = *(const bf16x8*)(Wm + (size_t)(d0 + ct * 16 + llo) * CH +
                                         ks * 32 + lhi * 8);
            acc[ct] = __builtin_amdgcn_mfma_f32_16x16x32_bf16(af[ks], bf, acc[ct], 0, 0, 0);
        }
    }

    u16* o = (mat ? k : q) + (size_t)n * LL * CH;
#pragma unroll
    for (int r = 0; r < 4; ++r) {
        int lr = l0 + w * 16 + lhi * 4 + r;
#pragma unroll
        for (int ct = 0; ct < 8; ++ct)
            o[(size_t)lr * CH + d0 + ct * 16 + llo] = f2b(acc[ct][r]);
    }
}

// ---------------------------------------------------------------------------
// Kernel 1b: v projection -> vT[n][d][l] bf16. A = Wv, B = xT.
// ---------------------------------------------------------------------------
__global__ __launch_bounds__(256, 1) void projv_kernel(
    const u16* __restrict__ xT, const u16* __restrict__ Wb,
    u16* __restrict__ vT) {
    const int n = blockIdx.z;
    const int d0 = blockIdx.y * 64;
    const int l0 = blockIdx.x * 128;
    const int tid = threadIdx.x;
    const int w = tid >> 6, lane = tid & 63;
    const int lhi = lane >> 4, llo = lane & 15;

    const u16* xn = xT + (size_t)n * LL * CH;
    const u16* Wm = Wb + 2 * 65536;

    bf16x8 af[8];
    const u16* abase = Wm + (size_t)(d0 + w * 16 + llo) * CH + lhi * 8;
#pragma unroll
    for (int ks = 0; ks < 8; ++ks) af[ks] = *(const bf16x8*)(abase + ks * 32);

    f32x4 acc[8];
#pragma unroll
    for (int t = 0; t < 8; ++t) acc[t] = (f32x4){0.f, 0.f, 0.f, 0.f};

#pragma unroll
    for (int ks = 0; ks < 8; ++ks) {
#pragma unroll
        for (int ct = 0; ct < 8; ++ct) {
            bf16x8 bf = *(const bf16x8*)(xn + (size_t)(l0 + ct * 16 + llo) * CH +
                                         ks * 32 + lhi * 8);
            acc[ct] = __builtin_amdgcn_mfma_f32_16x16x32_bf16(af[ks], bf, acc[ct], 0, 0, 0);
        }
    }

    u16* o = vT + (size_t)n * CH * LL;
#pragma unroll
    for (int r = 0; r < 4; ++r) {
        int dr = d0 + w * 16 + lhi * 4 + r;
#pragma unroll
        for (int ct = 0; ct < 8; ++ct)
            o[(size_t)dr * LL + l0 + ct * 16 + llo] = f2b(acc[ct][r]);
    }
}

// ---------------------------------------------------------------------------
// Kernel 2: bf16 flash attention, key-split, NO K/V STAGING (R12).
// R1 post-mortem: doubling arithmetic intensity per LDS byte gave only +9%
// (MfmaUtil 21->22) -> not LDS-BW bound; stall-bound. Per-iter cycle audit:
// MFMA work 2060 cyc/SIMD vs 9640 cyc measured. Stalls = per-iter vmcnt(0)
// barrier drain + 8-wave lockstep (VALU phase never overlaps MFMA phase
// across waves) at only 2 waves/SIMD.
// Fix (Common-mistake #7 precedent, m169 +26%): per-(n,s) K/V slice is 1 MB
// -> L2-fits. Drop LDS staging entirely; read K/V fragments straight from
// global (L1/L2-served, same fragment pattern as projqk's proven B-reads).
// No barriers at all -> waves drift into complementary phases; no vmcnt(0)
// drain. P stays in wave-private LDS (11 KB; no barrier: same-wave order via
// lgkmcnt). XCD-aware bijective remap keeps each XCD's L2 working set at 2
// (n,s) slices = 2 MB (< 4 MB/XCD); without it, round-robin would put all 16
// slices (16 MB) on every XCD. setprio(1) wraps MFMA clusters (m191: helps
// exactly in non-lockstep attn structures).
// ---------------------------------------------------------------------------
#define PSTRIDE 44

__global__ __launch_bounds__(256, 2) void fattn_kernel(
    const u16* __restrict__ q, const u16* __restrict__ k,
    const u16* __restrict__ vT, u16* __restrict__ Op, float* __restrict__ l_s,
    int iters, int S) {
    // bijective XCD-locality decode (dispatch round-robins id%8 across XCDs)
    const int id = blockIdx.x;
    const int nsT = NB * S;
    int ns, x;
    if (nsT >= 8) {
        const int cpx = nsT >> 3;           // (n,s) slices per XCD
        ns = (id & 7) * cpx + (id >> 8);    // id>>8 == (id>>3)/32
        x = (id >> 3) & 31;
    } else {
        x = id & 31;
        ns = id >> 5;
    }
    const int n = ns & (NB - 1);
    const int s_id = ns >> 2;
    const int l0 = x * 128;
    const int m_base = s_id * iters * 32;
    const int tid = threadIdx.x;
    const int w = tid >> 6;
    const int lane = tid & 63;
    const int lhi = lane >> 4, llo = lane & 15;

    __shared__ __align__(16) u16 Pbuf[128 * PSTRIDE];  // 11264 B, wave-private rows

    // ---- Q fragments (A-layout, bf16) direct from global: rows w*32+{0,16} ----
    bf16x8 qf[2][8];
    {
        const u16* base = q + (size_t)(n * LL + l0 + w * 32 + llo) * CH + lhi * 8;
#pragma unroll
        for (int t = 0; t < 2; ++t)
#pragma unroll
            for (int ks = 0; ks < 8; ++ks)
                qf[t][ks] = *(const bf16x8*)(base + t * 16 * CH + ks * 32);
    }

    // per-lane K/V base pointers (iter-advanced)
    const u16* kB = k + (size_t)n * LL * CH + (size_t)(m_base + llo) * CH + lhi * 8;
    const u16* vB = vT + (size_t)n * CH * LL + (size_t)llo * LL + m_base + lhi * 8;

    f32x4 oacc[2][16];
#pragma unroll
    for (int t = 0; t < 2; ++t)
#pragma unroll
        for (int ct = 0; ct < 16; ++ct) oacc[t][ct] = (f32x4){0.f, 0.f, 0.f, 0.f};
    float lrun[2][4] = {{0.f, 0.f, 0.f, 0.f}, {0.f, 0.f, 0.f, 0.f}};

    const float C1 = 0.09016844005556021f;  // (1/16) * log2(e)

    u16* pw0 = Pbuf + (w * 32) * PSTRIDE;
    u16* pw1 = Pbuf + (w * 32 + 16) * PSTRIDE;
    const u16* pr0 = Pbuf + (w * 32 + llo) * PSTRIDE + lhi * 8;
    const u16* pr1 = pr0 + 16 * PSTRIDE;

    for (int it = 0; it < iters; ++it) {
        // ---- S = Q·K^T : 2 row-tiles x 2 col-tiles x 8 k-steps.
        // K fragments read straight from global (L1/L2): same pattern as
        // projqk's B-read: K[m + llo (+16)][ks*32 + lhi*8 ..+8].
        f32x4 s00 = (f32x4){0.f, 0.f, 0.f, 0.f};
        f32x4 s01 = (f32x4){0.f, 0.f, 0.f, 0.f};
        f32x4 s10 = (f32x4){0.f, 0.f, 0.f, 0.f};
        f32x4 s11 = (f32x4){0.f, 0.f, 0.f, 0.f};
        __builtin_amdgcn_s_setprio(1);
#pragma unroll
        for (int ks = 0; ks < 8; ++ks) {
            bf16x8 b0 = *(const bf16x8*)(kB + ks * 32);
            bf16x8 b1 = *(const bf16x8*)(kB + 16 * CH + ks * 32);
            s00 = __builtin_amdgcn_mfma_f32_16x16x32_bf16(qf[0][ks], b0, s00, 0, 0, 0);
            s10 = __builtin_amdgcn_mfma_f32_16x16x32_bf16(qf[1][ks], b0, s10, 0, 0, 0);
            s01 = __builtin_amdgcn_mfma_f32_16x16x32_bf16(qf[0][ks], b1, s01, 0, 0, 0);
            s11 = __builtin_amdgcn_mfma_f32_16x16x32_bf16(qf[1][ks], b1, s11, 0, 0, 0);
        }
        __builtin_amdgcn_s_setprio(0);

        // ---- p = exp2(s * C1), write bf16 P; lrun += p ----
#pragma unroll
        for (int r = 0; r < 4; ++r) {
            int lrow = lhi * 4 + r;
            float p0 = __builtin_amdgcn_exp2f(s00[r] * C1);
            float p1 = __builtin_amdgcn_exp2f(s01[r] * C1);
            pw0[lrow * PSTRIDE + llo] = f2b(p0);
            pw0[lrow * PSTRIDE + 16 + llo] = f2b(p1);
            lrun[0][r] += p0 + p1;
            float p2 = __builtin_amdgcn_exp2f(s10[r] * C1);
            float p3 = __builtin_amdgcn_exp2f(s11[r] * C1);
            pw1[lrow * PSTRIDE + llo] = f2b(p2);
            pw1[lrow * PSTRIDE + 16 + llo] = f2b(p3);
            lrun[1][r] += p2 + p3;
        }

        // ---- PV (wave-private P rows; same-wave LDS round-trip, no barrier).
        // V^T fragments straight from global: V^T[d = ct*16+llo][m0 + lhi*8].
        bf16x8 pf0 = *(const bf16x8*)pr0;
        bf16x8 pf1 = *(const bf16x8*)pr1;
        __builtin_amdgcn_s_setprio(1);
#pragma unroll
        for (int ct = 0; ct < 16; ++ct) {
            bf16x8 vf = *(const bf16x8*)(vB + (size_t)ct * 16 * LL);
            oacc[0][ct] = __builtin_amdgcn_mfma_f32_16x16x32_bf16(pf0, vf, oacc[0][ct], 0, 0, 0);
            oacc[1][ct] = __builtin_amdgcn_mfma_f32_16x16x32_bf16(pf1, vf, oacc[1][ct], 0, 0, 0);
        }
        __builtin_amdgcn_s_setprio(0);

        kB += 32 * CH;
        vB += 32;
    }

    // ---- epilogue: store un-normalized partial O (bf16) + l (fp32) ----
    u16* ap = Op + (size_t)((s_id * NB + n) * (size_t)LL + l0 + w * 32) * CH;
    float* lp = l_s + (size_t)s_id * NB * LL + (size_t)n * LL + l0 + w * 32;
#pragma unroll
    for (int t = 0; t < 2; ++t) {
#pragma unroll
        for (int r = 0; r < 4; ++r) {
            float ls = lrun[t][r];
            ls += __shfl_xor(ls, 1);
            ls += __shfl_xor(ls, 2);
            ls += __shfl_xor(ls, 4);
            ls += __shfl_xor(ls, 8);
            int lrow = t * 16 + lhi * 4 + r;
#pragma unroll
            for (int ct = 0; ct < 16; ++ct) {
                ap[(size_t)lrow * CH + ct * 16 + llo] = f2b(oacc[t][ct][r]);
            }
            if (llo == 0) lp[lrow] = ls;
        }
    }
}

// ---------------------------------------------------------------------------
// Kernel 2c: merge splits: att[i] = (sum_s Op[s][i]) / (sum_s l_s[s][row])
// ---------------------------------------------------------------------------
__global__ __launch_bounds__(256) void merge_kernel(
    const u16* __restrict__ Op, const float* __restrict__ l_s,
    u16* __restrict__ att, int S) {
    const size_t t8 = (size_t)blockIdx.x * 256 + threadIdx.x;
    const size_t flat = t8 * 8;
    const size_t row = flat >> 8;
    float lsum = 0.0f;
    for (int s = 0; s < S; ++s) lsum += l_s[(size_t)s * NB * LL + row];
    const float inv = 1.0f / lsum;
    float acc[8];
#pragma unroll
    for (int j = 0; j < 8; ++j) acc[j] = 0.0f;
    for (int s = 0; s < S; ++s) {
        uint4 raw = *(const uint4*)(Op + (size_t)s * NB * LL * CH + flat);
        acc[0] += blo(raw.x); acc[1] += bhi(raw.x);
        acc[2] += blo(raw.y); acc[3] += bhi(raw.y);
        acc[4] += blo(raw.z); acc[5] += bhi(raw.z);
        acc[6] += blo(raw.w); acc[7] += bhi(raw.w);
    }
    uint4 o;
    o.x = pack2(acc[0] * inv, acc[1] * inv);
    o.y = pack2(acc[2] * inv, acc[3] * inv);
    o.z = pack2(acc[4] * inv, acc[5] * inv);
    o.w = pack2(acc[6] * inv, acc[7] * inv);
    *(uint4*)(att + flat) = o;
}

// ---------------------------------------------------------------------------
// Kernel 3: output projection via MFMA + fused BN partial sums. y bf16.
// ---------------------------------------------------------------------------
__global__ __launch_bounds__(256, 1) void outm_kernel(
    const u16* __restrict__ Wb, const u16* __restrict__ att,
    u16* __restrict__ y, float* __restrict__ stats) {
    const int n = blockIdx.z;
    const int o0 = blockIdx.y * 64;
    const int l0 = blockIdx.x * 128;
    const int tid = threadIdx.x;
    const int w = tid >> 6, lane = tid & 63;
    const int lhi = lane >> 4, llo = lane & 15;

    const u16* an = att + (size_t)n * LL * CH;
    const u16* Wm = Wb + 3 * 65536;

    bf16x8 af[8];
    const u16* abase = Wm + (size_t)(o0 + w * 16 + llo) * CH + lhi * 8;
#pragma unroll
    for (int ks = 0; ks < 8; ++ks) af[ks] = *(const bf16x8*)(abase + ks * 32);

    f32x4 acc[8];
#pragma unroll
    for (int t = 0; t < 8; ++t) acc[t] = (f32x4){0.f, 0.f, 0.f, 0.f};

#pragma unroll
    for (int ks = 0; ks < 8; ++ks) {
#pragma unroll
        for (int ct = 0; ct < 8; ++ct) {
            bf16x8 bf = *(const bf16x8*)(an + (size_t)(l0 + ct * 16 + llo) * CH +
                                         ks * 32 + lhi * 8);
            acc[ct] = __builtin_amdgcn_mfma_f32_16x16x32_bf16(af[ks], bf, acc[ct], 0, 0, 0);
        }
    }

    u16* yn = y + (size_t)n * CH * LL;
#pragma unroll
    for (int r = 0; r < 4; ++r) {
        const int orow = o0 + w * 16 + lhi * 4 + r;
        float ts = 0.0f, tq = 0.0f;
#pragma unroll
        for (int ct = 0; ct < 8; ++ct) {
            float vv = acc[ct][r];
            yn[(size_t)orow * LL + l0 + ct * 16 + llo] = f2b(vv);
            ts += vv;
            tq += vv * vv;
        }
        ts += __shfl_xor(ts, 1); tq += __shfl_xor(tq, 1);
        ts += __shfl_xor(ts, 2); tq += __shfl_xor(tq, 2);
        ts += __shfl_xor(ts, 4); tq += __shfl_xor(tq, 4);
        ts += __shfl_xor(ts, 8); tq += __shfl_xor(tq, 8);
        if (llo == 0) {
            atomicAdd(&stats[orow], ts);
            atomicAdd(&stats[256 + orow], tq);
        }
    }
}

// ---------------------------------------------------------------------------
// Kernel 4: BN apply (batch stats, biased var) + residual. y read as bf16.
// ---------------------------------------------------------------------------
__global__ __launch_bounds__(256) void bn_kernel(
    const float* __restrict__ x, const u16* __restrict__ y,
    const float* __restrict__ stats, const float* __restrict__ gamma,
    const float* __restrict__ beta, float* __restrict__ out) {
    const int idx = blockIdx.x * 256 + threadIdx.x;  // per 4 elems
    const int base = idx * 4;
    const int c = (base >> 12) & 255;  // (base / L) % C
    const float cnt = 1.0f / 16384.0f; // N*L
    float mean = stats[c] * cnt;
    float var = stats[256 + c] * cnt - mean * mean;
    float rstd = rsqrtf(var + 1e-4f);
    float g = gamma[c] * rstd;
    float b = beta[c];
    uint2 yv = ((const uint2*)y)[idx];
    float4 xv = ((const float4*)x)[idx];
    float4 o;
    o.x = xv.x + (blo(yv.x) - mean) * g + b;
    o.y = xv.y + (bhi(yv.x) - mean) * g + b;
    o.z = xv.z + (blo(yv.y) - mean) * g + b;
    o.w = xv.w + (bhi(yv.y) - mean) * g + b;
    ((float4*)out)[idx] = o;
}

// ---------------------------------------------------------------------------
extern "C" void kernel_launch(void* const* d_in, const int* in_sizes, int n_in,
                              void* d_out, int out_size, void* d_ws, size_t ws_size,
                              hipStream_t stream) {
    const float* x = (const float*)d_in[0];
    const float* Wq = (const float*)d_in[1];
    const float* Wk = (const float*)d_in[2];
    const float* Wv = (const float*)d_in[3];
    const float* Wo = (const float*)d_in[4];
    const float* gamma = (const float*)d_in[5];
    const float* beta = (const float*)d_in[6];
    float* out = (float*)d_out;

    const size_t elems = (size_t)NB * LL * CH;  // 4,194,304

    // pick largest split count whose workspace fits (S=4 needs ~59.4 MB)
    int S = 1;
    for (int cand = 4; cand >= 2; cand >>= 1) {
        size_t need = elems * 2 * (size_t)(3 + cand) +
                      (size_t)cand * NB * LL * 4 + 524288 + 8192;
        if (ws_size >= need) { S = cand; break; }
    }
    const int iters = 128 / S;

    char* wsb = (char*)d_ws;
    u16* q = (u16*)wsb;                             // 8.39 MB (bf16)
    u16* k = q + elems;                             // 8.39 MB (bf16)
    u16* vT = k + elems;                            // 8.39 MB (bf16)
    u16* Op = vT + elems;                           // S * 8.39 MB (bf16)
    u16* xT = Op;                                   // overlay: dead before fattn
    float* l_s = (float*)(Op + (size_t)S * elems);  // S * 64 KB
    u16* Wb = (u16*)(l_s + (size_t)S * NB * LL);    // 512 KB
    float* stats = (float*)(Wb + 4 * 65536);        // 2 KB
    u16* att = q;   // overlay q (dead after fattn)
    u16* y = k;     // overlay k (dead after merge)

    castw_kernel<<<dim3(64, 4), 256, 0, stream>>>(Wq, Wk, Wv, Wo, Wb, stats);
    tcast_kernel<<<dim3(LL / 64, CH / 64, NB), 256, 0, stream>>>(x, xT);
    projqk_kernel<<<dim3(LL / 64, 4, NB), 256, 0, stream>>>(xT, Wb, q, k);
    projv_kernel<<<dim3(LL / 128, CH / 64, NB), 256, 0, stream>>>(xT, Wb, vT);
    fattn_kernel<<<dim3(32 * NB * S), 256, 0, stream>>>(q, k, vT, Op, l_s, iters, S);
    merge_kernel<<<(int)(elems / 8 / 256), 256, 0, stream>>>(Op, l_s, att, S);
    outm_kernel<<<dim3(LL / 128, CH / 64, NB), 256, 0, stream>>>(Wb, att, y, stats);
    bn_kernel<<<(NB * CH * LL / 4) / 256, 256, 0, stream>>>(x, y, stats, gamma, beta, out);
}

// Round 3
// 257.480 us; speedup vs baseline: 1.6325x; 1.6325x over previous
//
#include <hip/hip_runtime.h>
#include <cstdint>
#include <cstddef>

// Problem constants: N=4, C=D=256, H=W=64, L=4096
#define NB 4
#define CH 256
#define LL 4096

typedef unsigned short u16;
typedef unsigned int u32;
typedef unsigned char u8;
typedef __attribute__((ext_vector_type(8))) short bf16x8;
typedef __attribute__((ext_vector_type(4))) float f32x4;

#define GPTR(p) ((const __attribute__((address_space(1))) u32*)(p))
#define LPTR(p) ((__attribute__((address_space(3))) u32*)(p))

__device__ __forceinline__ float blo(u32 x) { return __uint_as_float(x << 16); }
__device__ __forceinline__ float bhi(u32 x) { return __uint_as_float(x & 0xffff0000u); }
__device__ __forceinline__ float b2f(u16 h) { return __uint_as_float(((u32)h) << 16); }
__device__ __forceinline__ u16 f2b(float f) {
    u32 u = __float_as_uint(f);
    u32 r = (u + 0x7fffu + ((u >> 16) & 1u)) >> 16;  // RNE
    return (u16)r;
}
__device__ __forceinline__ u32 pack2(float a, float b) {
    return (u32)f2b(a) | ((u32)f2b(b) << 16);
}

// ---------------------------------------------------------------------------
// Kernel 0b: cast weights to bf16 (Wb[mat][d][c]) + zero BN stats.
// ---------------------------------------------------------------------------
__global__ __launch_bounds__(256) void castw_kernel(
    const float* __restrict__ Wq, const float* __restrict__ Wk,
    const float* __restrict__ Wv, const float* __restrict__ Wo,
    u16* __restrict__ Wb, float* __restrict__ stats) {
    const int i = blockIdx.x * 256 + threadIdx.x;
    const int m = blockIdx.y;
    if (m == 0 && blockIdx.x < 2) stats[i] = 0.0f;
    const float* src = (m == 0) ? Wq : (m == 1) ? Wk : (m == 2) ? Wv : Wo;
    float4 v = ((const float4*)src)[i];
    uint2 o;
    o.x = pack2(v.x, v.y);
    o.y = pack2(v.z, v.w);
    ((uint2*)(Wb + m * 65536))[i] = o;
}

// ---------------------------------------------------------------------------
// Kernel 0c: transpose-cast x[n][c][l] f32 -> xT[n][l][c] bf16 (64x64 tiles).
// ---------------------------------------------------------------------------
__global__ __launch_bounds__(256) void tcast_kernel(
    const float* __restrict__ x, u16* __restrict__ xT) {
    const int n = blockIdx.z;
    const int c0 = blockIdx.y * 64, l0 = blockIdx.x * 64;
    __shared__ u16 t[64][72];
    const float* xs = x + (size_t)n * CH * LL;
    const int tid = threadIdx.x;
    const int lq = (tid & 15) * 4, cc = tid >> 4;
#pragma unroll
    for (int p = 0; p < 4; ++p) {
        int c = cc + p * 16;
        float4 v = *(const float4*)&xs[(size_t)(c0 + c) * LL + l0 + lq];
        t[lq + 0][c] = f2b(v.x);
        t[lq + 1][c] = f2b(v.y);
        t[lq + 2][c] = f2b(v.z);
        t[lq + 3][c] = f2b(v.w);
    }
    __syncthreads();
    u16* xo = xT + (size_t)n * LL * CH;
    const int l = tid >> 2, c8 = (tid & 3) * 16;
#pragma unroll
    for (int h = 0; h < 2; ++h) {
        uint4 vv = *(uint4*)&t[l][c8 + h * 8];
        *(uint4*)&xo[(size_t)(l0 + l) * CH + c0 + c8 + h * 8] = vv;
    }
}

// ---------------------------------------------------------------------------
// Kernel 1a: q/k projections via bf16 MFMA, output bf16. (fp8 q/k is the
// correlated-error path: R9 absmax 0.22 -- must stay bf16.)
// ---------------------------------------------------------------------------
__global__ __launch_bounds__(256, 1) void projqk_kernel(
    const u16* __restrict__ xT, const u16* __restrict__ Wb,
    u16* __restrict__ q, u16* __restrict__ k) {
    const int n = blockIdx.z;
    const int dhalf = blockIdx.y & 1, mat = blockIdx.y >> 1;
    const int l0 = blockIdx.x * 64;
    const int d0 = dhalf * 128;
    const int tid = threadIdx.x;
    const int w = tid >> 6, lane = tid & 63;
    const int lhi = lane >> 4, llo = lane & 15;

    const u16* xn = xT + (size_t)n * LL * CH;
    const u16* Wm = Wb + mat * 65536;

    bf16x8 af[8];
    const u16* abase = xn + (size_t)(l0 + w * 16 + llo) * CH + lhi * 8;
#pragma unroll
    for (int ks = 0; ks < 8; ++ks) af[ks] = *(const bf16x8*)(abase + ks * 32);

    f32x4 acc[8];
#pragma unroll
    for (int t = 0; t < 8; ++t) acc[t] = (f32x4){0.f, 0.f, 0.f, 0.f};

#pragma unroll
    for (int ks = 0; ks < 8; ++ks) {
#pragma unroll
        for (int ct = 0; ct < 8; ++ct) {
            bf16x8 bf = *(const bf16x8*)(Wm + (size_t)(d0 + ct * 16 + llo) * CH +
                                         ks * 32 + lhi * 8);
            acc[ct] = __builtin_amdgcn_mfma_f32_16x16x32_bf16(af[ks], bf, acc[ct], 0, 0, 0);
        }
    }

    u16* o = (mat ? k : q) + (size_t)n * LL * CH;
#pragma unroll
    for (int r = 0; r < 4; ++r) {
        int lr = l0 + w * 16 + lhi * 4 + r;
#pragma unroll
        for (int ct = 0; ct < 8; ++ct)
            o[(size_t)lr * CH + d0 + ct * 16 + llo] = f2b(acc[ct][r]);
    }
}

// ---------------------------------------------------------------------------
// Kernel 1b: v projection -> vT[n][d][l] bf16. A = Wv, B = xT.
// ---------------------------------------------------------------------------
__global__ __launch_bounds__(256, 1) void projv_kernel(
    const u16* __restrict__ xT, const u16* __restrict__ Wb,
    u16* __restrict__ vT) {
    const int n = blockIdx.z;
    const int d0 = blockIdx.y * 64;
    const int l0 = blockIdx.x * 128;
    const int tid = threadIdx.x;
    const int w = tid >> 6, lane = tid & 63;
    const int lhi = lane >> 4, llo = lane & 15;

    const u16* xn = xT + (size_t)n * LL * CH;
    const u16* Wm = Wb + 2 * 65536;

    bf16x8 af[8];
    const u16* abase = Wm + (size_t)(d0 + w * 16 + llo) * CH + lhi * 8;
#pragma unroll
    for (int ks = 0; ks < 8; ++ks) af[ks] = *(const bf16x8*)(abase + ks * 32);

    f32x4 acc[8];
#pragma unroll
    for (int t = 0; t < 8; ++t) acc[t] = (f32x4){0.f, 0.f, 0.f, 0.f};

#pragma unroll
    for (int ks = 0; ks < 8; ++ks) {
#pragma unroll
        for (int ct = 0; ct < 8; ++ct) {
            bf16x8 bf = *(const bf16x8*)(xn + (size_t)(l0 + ct * 16 + llo) * CH +
                                         ks * 32 + lhi * 8);
            acc[ct] = __builtin_amdgcn_mfma_f32_16x16x32_bf16(af[ks], bf, acc[ct], 0, 0, 0);
        }
    }

    u16* o = vT + (size_t)n * CH * LL;
#pragma unroll
    for (int r = 0; r < 4; ++r) {
        int dr = d0 + w * 16 + lhi * 4 + r;
#pragma unroll
        for (int ct = 0; ct < 8; ++ct)
            o[(size_t)dr * LL + l0 + ct * 16 + llo] = f2b(acc[ct][r]);
    }
}

// ---------------------------------------------------------------------------
// Kernel 2: bf16 flash attention, key-split, DOUBLE-BUFFERED K/V tiles (R13).
// R2 post-mortem: no-staging regressed 2x (per-MFMA L2 latency exposed);
// reverted to R1 staging. R1 post-mortem: stall is the per-iter serial chain
// QK -> exp2 -> 64 f2b VALU -> ds_write P -> lgkmcnt(0) -> ds_read P -> PV
// (the P LDS round-trip), in lockstep across waves.
// R13 = SWAPPED QK^T (T12-analog, m214 v22): compute mfma(A=K, B=Q). R1's
// LDS K-read is already the correct A-fragment and qf the correct B-fragment
// (A/B layouts symmetric), so the swap is free. Output is q-row-lane-local:
// lane holds P[qrow=llo][m=kt*16+4*lhi+r]. P->PV A-frag built IN-REGISTER:
// 8 cvt_pk_bf16_f32 (replaces 64 f2b ops) + 16 ds_bpermute + 8 cndmask per
// wave-iter. No P LDS buffer, no ds_write, no lgkmcnt(0) drain, no stride-44
// bank conflicts. PV output layout verified identical to R1's epilogue.
// lrun reduction moves to shfl_xor 16/32 (over lhi). LDS 65536 B:
// K[2][32][256] | V[2][256][32] (chunk-XOR swizzles, unchanged). 2 blk/CU.
// ---------------------------------------------------------------------------
__global__ __launch_bounds__(256, 2) void fattn_kernel(
    const u16* __restrict__ q, const u16* __restrict__ k,
    const u16* __restrict__ vT, u16* __restrict__ Op, float* __restrict__ l_s,
    int iters) {
    const int n = blockIdx.y;
    const int s_id = blockIdx.z;
    const int l0 = blockIdx.x * 128;
    const int m_base = s_id * iters * 32;
    const int tid = threadIdx.x;
    const int w = tid >> 6;
    const int lane = tid & 63;
    const int lhi = lane >> 4, llo = lane & 15;

    __shared__ __align__(16) char smem[65536];
    // K buffers @ 0 / 16384 ; V buffers @ 32768 / 49152

    // ---- Q fragments (bf16) direct from global: rows w*32+{0,16}.
    // Serve as the MFMA B-operand in the swapped QK^T (col=llo -> q-row). ----
    bf16x8 qf[2][8];
    {
        const u16* base = q + (size_t)(n * LL + l0 + w * 32 + llo) * CH + lhi * 8;
#pragma unroll
        for (int t = 0; t < 2; ++t)
#pragma unroll
            for (int ks = 0; ks < 8; ++ks)
                qf[t][ks] = *(const bf16x8*)(base + t * 16 * CH + ks * 32);
    }

    const u16* kg = k + (size_t)n * LL * CH;
    const u16* vg = vT + (size_t)n * CH * LL;

    // iter-invariant swizzled offsets (u16 elems); slot s = i*256 + tid
    int okK[4], okV[4];
#pragma unroll
    for (int i = 0; i < 4; ++i) {
        int s = i * 256 + tid;
        int rK = s >> 5;
        int cK = (s & 31) ^ rK;
        okK[i] = rK * CH + cK * 8;
        int dV = s >> 2;
        int cV = (s & 3) ^ ((dV & 3) ^ ((dV >> 2) & 3));
        okV[i] = dV * LL + cV * 8;
    }

    f32x4 oacc[2][16];
#pragma unroll
    for (int t = 0; t < 2; ++t)
#pragma unroll
        for (int ct = 0; ct < 16; ++ct) oacc[t][ct] = (f32x4){0.f, 0.f, 0.f, 0.f};
    float lrun[2] = {0.f, 0.f};

    const float C1 = 0.09016844005556021f;  // (1/16) * log2(e)
    const int posV = (lhi ^ ((llo & 3) ^ (llo >> 2))) * 8;
    // bpermute gather indices (bytes): group (2*(lhi&1)) and (2*(lhi&1))+1
    const int idxA = (llo + 32 * (lhi & 1)) * 4;
    const int idxB = idxA + 64;
    const bool selLo = (lhi < 2);

    // ---- prologue: issue tile 0 into buffer 0 ----
    {
        const u16* kg2 = kg + (size_t)m_base * CH;
        const u16* vg2 = vg + m_base;
#pragma unroll
        for (int i = 0; i < 4; ++i) {
            __builtin_amdgcn_global_load_lds(GPTR(kg2 + okK[i]),
                                             LPTR(smem + i * 4096 + w * 1024), 16, 0, 0);
            __builtin_amdgcn_global_load_lds(GPTR(vg2 + okV[i]),
                                             LPTR(smem + 32768 + i * 4096 + w * 1024),
                                             16, 0, 0);
        }
    }

    for (int it = 0; it < iters; ++it) {
        __syncthreads();  // drains tile-it loads; prev compute done with other buf
        if (it + 1 < iters) {
            const int m1 = m_base + (it + 1) * 32;
            const u16* kg2 = kg + (size_t)m1 * CH;
            const u16* vg2 = vg + m1;
            char* Kb = smem + ((it + 1) & 1) * 16384;
            char* Vb = smem + 32768 + ((it + 1) & 1) * 16384;
#pragma unroll
            for (int i = 0; i < 4; ++i) {
                __builtin_amdgcn_global_load_lds(GPTR(kg2 + okK[i]),
                                                 LPTR(Kb + i * 4096 + w * 1024), 16, 0, 0);
                __builtin_amdgcn_global_load_lds(GPTR(vg2 + okV[i]),
                                                 LPTR(Vb + i * 4096 + w * 1024), 16, 0, 0);
            }
        }
        const u16* Kl = (const u16*)(smem + (it & 1) * 16384);
        const u16* Vl = (const u16*)(smem + 32768 + (it & 1) * 16384);

        // ---- S^T = K·Q^T (swapped): s[qt][kt], lane holds q-row llo,
        // k-cols kt*16 + lhi*4 + r. Same LDS reads as before (b0/b1 are the
        // A-fragment now; qf is the B-fragment). ----
        f32x4 s00 = (f32x4){0.f, 0.f, 0.f, 0.f};
        f32x4 s01 = (f32x4){0.f, 0.f, 0.f, 0.f};
        f32x4 s10 = (f32x4){0.f, 0.f, 0.f, 0.f};
        f32x4 s11 = (f32x4){0.f, 0.f, 0.f, 0.f};
#pragma unroll
        for (int ks = 0; ks < 8; ++ks) {
            const int cq = ks * 4 + lhi;
            bf16x8 b0 = *(const bf16x8*)(Kl + llo * 256 + (cq ^ llo) * 8);
            bf16x8 b1 = *(const bf16x8*)(Kl + (llo + 16) * 256 + (cq ^ (llo + 16)) * 8);
            s00 = __builtin_amdgcn_mfma_f32_16x16x32_bf16(b0, qf[0][ks], s00, 0, 0, 0);
            s10 = __builtin_amdgcn_mfma_f32_16x16x32_bf16(b0, qf[1][ks], s10, 0, 0, 0);
            s01 = __builtin_amdgcn_mfma_f32_16x16x32_bf16(b1, qf[0][ks], s01, 0, 0, 0);
            s11 = __builtin_amdgcn_mfma_f32_16x16x32_bf16(b1, qf[1][ks], s11, 0, 0, 0);
        }

        // ---- p = exp2(s*C1); pack bf16 pairs in-register; gather A-frags.
        // Lane (llo,lhi) has k = {4lhi..4lhi+3} (w0,w1) and {16+4lhi..} (w2,w3)
        // for q-row qt*16+llo; A-frag needs k = {8lhi..8lhi+7}. ----
        bf16x8 pa[2];
#pragma unroll
        for (int qt = 0; qt < 2; ++qt) {
            f32x4 sa = qt ? s10 : s00;   // kt = 0
            f32x4 sb = qt ? s11 : s01;   // kt = 1
            float pA0 = __builtin_amdgcn_exp2f(sa[0] * C1);
            float pA1 = __builtin_amdgcn_exp2f(sa[1] * C1);
            float pA2 = __builtin_amdgcn_exp2f(sa[2] * C1);
            float pA3 = __builtin_amdgcn_exp2f(sa[3] * C1);
            float pB0 = __builtin_amdgcn_exp2f(sb[0] * C1);
            float pB1 = __builtin_amdgcn_exp2f(sb[1] * C1);
            float pB2 = __builtin_amdgcn_exp2f(sb[2] * C1);
            float pB3 = __builtin_amdgcn_exp2f(sb[3] * C1);
            lrun[qt] += ((pA0 + pA1) + (pA2 + pA3)) + ((pB0 + pB1) + (pB2 + pB3));
            u32 w0, w1, w2, w3;
            asm("v_cvt_pk_bf16_f32 %0, %1, %2" : "=v"(w0) : "v"(pA0), "v"(pA1));
            asm("v_cvt_pk_bf16_f32 %0, %1, %2" : "=v"(w1) : "v"(pA2), "v"(pA3));
            asm("v_cvt_pk_bf16_f32 %0, %1, %2" : "=v"(w2) : "v"(pB0), "v"(pB1));
            asm("v_cvt_pk_bf16_f32 %0, %1, %2" : "=v"(w3) : "v"(pB2), "v"(pB3));
            int t0 = __builtin_amdgcn_ds_bpermute(idxA, (int)w0);
            int t2 = __builtin_amdgcn_ds_bpermute(idxA, (int)w2);
            int u0 = __builtin_amdgcn_ds_bpermute(idxA, (int)w1);
            int u2 = __builtin_amdgcn_ds_bpermute(idxA, (int)w3);
            int v0 = __builtin_amdgcn_ds_bpermute(idxB, (int)w0);
            int v2 = __builtin_amdgcn_ds_bpermute(idxB, (int)w2);
            int x0 = __builtin_amdgcn_ds_bpermute(idxB, (int)w1);
            int x2 = __builtin_amdgcn_ds_bpermute(idxB, (int)w3);
            union { u32 u[4]; bf16x8 v; } pk;
            pk.u[0] = selLo ? (u32)t0 : (u32)t2;
            pk.u[1] = selLo ? (u32)u0 : (u32)u2;
            pk.u[2] = selLo ? (u32)v0 : (u32)v2;
            pk.u[3] = selLo ? (u32)x0 : (u32)x2;
            pa[qt] = pk.v;
        }

        // ---- PV: A=pa (q-rows lane-local), B=vf (unchanged). Output layout
        // identical to R1: oacc[qt][ct][r] = O[qt*16+lhi*4+r][ct*16+llo]. ----
#pragma unroll
        for (int ct = 0; ct < 16; ++ct) {
            bf16x8 vf = *(const bf16x8*)(Vl + (ct * 16 + llo) * 32 + posV);
            oacc[0][ct] = __builtin_amdgcn_mfma_f32_16x16x32_bf16(pa[0], vf, oacc[0][ct], 0, 0, 0);
            oacc[1][ct] = __builtin_amdgcn_mfma_f32_16x16x32_bf16(pa[1], vf, oacc[1][ct], 0, 0, 0);
        }
    }

    // ---- epilogue: store un-normalized partial O (bf16) + l (fp32).
    // lrun[qt] at lane (llo,lhi): partial row-sum for q-row qt*16+llo over
    // k in {4lhi..} -- reduce across lhi groups (xor 16, 32). ----
    u16* ap = Op + (size_t)((s_id * NB + n) * (size_t)LL + l0 + w * 32) * CH;
    float* lp = l_s + (size_t)s_id * NB * LL + (size_t)n * LL + l0 + w * 32;
#pragma unroll
    for (int t = 0; t < 2; ++t) {
        float ls = lrun[t];
        ls += __shfl_xor(ls, 16);
        ls += __shfl_xor(ls, 32);
        if (lhi == 0) lp[t * 16 + llo] = ls;
#pragma unroll
        for (int r = 0; r < 4; ++r) {
            int lrow = t * 16 + lhi * 4 + r;
#pragma unroll
            for (int ct = 0; ct < 16; ++ct) {
                ap[(size_t)lrow * CH + ct * 16 + llo] = f2b(oacc[t][ct][r]);
            }
        }
    }
}

// ---------------------------------------------------------------------------
// Kernel 2c: merge splits: att[i] = (sum_s Op[s][i]) / (sum_s l_s[s][row])
// ---------------------------------------------------------------------------
__global__ __launch_bounds__(256) void merge_kernel(
    const u16* __restrict__ Op, const float* __restrict__ l_s,
    u16* __restrict__ att, int S) {
    const size_t t8 = (size_t)blockIdx.x * 256 + threadIdx.x;
    const size_t flat = t8 * 8;
    const size_t row = flat >> 8;
    float lsum = 0.0f;
    for (int s = 0; s < S; ++s) lsum += l_s[(size_t)s * NB * LL + row];
    const float inv = 1.0f / lsum;
    float acc[8];
#pragma unroll
    for (int j = 0; j < 8; ++j) acc[j] = 0.0f;
    for (int s = 0; s < S; ++s) {
        uint4 raw = *(const uint4*)(Op + (size_t)s * NB * LL * CH + flat);
        acc[0] += blo(raw.x); acc[1] += bhi(raw.x);
        acc[2] += blo(raw.y); acc[3] += bhi(raw.y);
        acc[4] += blo(raw.z); acc[5] += bhi(raw.z);
        acc[6] += blo(raw.w); acc[7] += bhi(raw.w);
    }
    uint4 o;
    o.x = pack2(acc[0] * inv, acc[1] * inv);
    o.y = pack2(acc[2] * inv, acc[3] * inv);
    o.z = pack2(acc[4] * inv, acc[5] * inv);
    o.w = pack2(acc[6] * inv, acc[7] * inv);
    *(uint4*)(att + flat) = o;
}

// ---------------------------------------------------------------------------
// Kernel 3: output projection via MFMA + fused BN partial sums. y bf16.
// ---------------------------------------------------------------------------
__global__ __launch_bounds__(256, 1) void outm_kernel(
    const u16* __restrict__ Wb, const u16* __restrict__ att,
    u16* __restrict__ y, float* __restrict__ stats) {
    const int n = blockIdx.z;
    const int o0 = blockIdx.y * 64;
    const int l0 = blockIdx.x * 128;
    const int tid = threadIdx.x;
    const int w = tid >> 6, lane = tid & 63;
    const int lhi = lane >> 4, llo = lane & 15;

    const u16* an = att + (size_t)n * LL * CH;
    const u16* Wm = Wb + 3 * 65536;

    bf16x8 af[8];
    const u16* abase = Wm + (size_t)(o0 + w * 16 + llo) * CH + lhi * 8;
#pragma unroll
    for (int ks = 0; ks < 8; ++ks) af[ks] = *(const bf16x8*)(abase + ks * 32);

    f32x4 acc[8];
#pragma unroll
    for (int t = 0; t < 8; ++t) acc[t] = (f32x4){0.f, 0.f, 0.f, 0.f};

#pragma unroll
    for (int ks = 0; ks < 8; ++ks) {
#pragma unroll
        for (int ct = 0; ct < 8; ++ct) {
            bf16x8 bf = *(const bf16x8*)(an + (size_t)(l0 + ct * 16 + llo) * CH +
                                         ks * 32 + lhi * 8);
            acc[ct] = __builtin_amdgcn_mfma_f32_16x16x32_bf16(af[ks], bf, acc[ct], 0, 0, 0);
        }
    }

    u16* yn = y + (size_t)n * CH * LL;
#pragma unroll
    for (int r = 0; r < 4; ++r) {
        const int orow = o0 + w * 16 + lhi * 4 + r;
        float ts = 0.0f, tq = 0.0f;
#pragma unroll
        for (int ct = 0; ct < 8; ++ct) {
            float vv = acc[ct][r];
            yn[(size_t)orow * LL + l0 + ct * 16 + llo] = f2b(vv);
            ts += vv;
            tq += vv * vv;
        }
        ts += __shfl_xor(ts, 1); tq += __shfl_xor(tq, 1);
        ts += __shfl_xor(ts, 2); tq += __shfl_xor(tq, 2);
        ts += __shfl_xor(ts, 4); tq += __shfl_xor(tq, 4);
        ts += __shfl_xor(ts, 8); tq += __shfl_xor(tq, 8);
        if (llo == 0) {
            atomicAdd(&stats[orow], ts);
            atomicAdd(&stats[256 + orow], tq);
        }
    }
}

// ---------------------------------------------------------------------------
// Kernel 4: BN apply (batch stats, biased var) + residual. y read as bf16.
// ---------------------------------------------------------------------------
__global__ __launch_bounds__(256) void bn_kernel(
    const float* __restrict__ x, const u16* __restrict__ y,
    const float* __restrict__ stats, const float* __restrict__ gamma,
    const float* __restrict__ beta, float* __restrict__ out) {
    const int idx = blockIdx.x * 256 + threadIdx.x;  // per 4 elems
    const int base = idx * 4;
    const int c = (base >> 12) & 255;  // (base / L) % C
    const float cnt = 1.0f / 16384.0f; // N*L
    float mean = stats[c] * cnt;
    float var = stats[256 + c] * cnt - mean * mean;
    float rstd = rsqrtf(var + 1e-4f);
    float g = gamma[c] * rstd;
    float b = beta[c];
    uint2 yv = ((const uint2*)y)[idx];
    float4 xv = ((const float4*)x)[idx];
    float4 o;
    o.x = xv.x + (blo(yv.x) - mean) * g + b;
    o.y = xv.y + (bhi(yv.x) - mean) * g + b;
    o.z = xv.z + (blo(yv.y) - mean) * g + b;
    o.w = xv.w + (bhi(yv.y) - mean) * g + b;
    ((float4*)out)[idx] = o;
}

// ---------------------------------------------------------------------------
extern "C" void kernel_launch(void* const* d_in, const int* in_sizes, int n_in,
                              void* d_out, int out_size, void* d_ws, size_t ws_size,
                              hipStream_t stream) {
    const float* x = (const float*)d_in[0];
    const float* Wq = (const float*)d_in[1];
    const float* Wk = (const float*)d_in[2];
    const float* Wv = (const float*)d_in[3];
    const float* Wo = (const float*)d_in[4];
    const float* gamma = (const float*)d_in[5];
    const float* beta = (const float*)d_in[6];
    float* out = (float*)d_out;

    const size_t elems = (size_t)NB * LL * CH;  // 4,194,304

    // pick largest split count whose workspace fits (S=4 needs ~59.4 MB)
    int S = 1;
    for (int cand = 4; cand >= 2; cand >>= 1) {
        size_t need = elems * 2 * (size_t)(3 + cand) +
                      (size_t)cand * NB * LL * 4 + 524288 + 8192;
        if (ws_size >= need) { S = cand; break; }
    }
    const int iters = 128 / S;

    char* wsb = (char*)d_ws;
    u16* q = (u16*)wsb;                             // 8.39 MB (bf16)
    u16* k = q + elems;                             // 8.39 MB (bf16)
    u16* vT = k + elems;                            // 8.39 MB (bf16)
    u16* Op = vT + elems;                           // S * 8.39 MB (bf16)
    u16* xT = Op;                                   // overlay: dead before fattn
    float* l_s = (float*)(Op + (size_t)S * elems);  // S * 64 KB
    u16* Wb = (u16*)(l_s + (size_t)S * NB * LL);    // 512 KB
    float* stats = (float*)(Wb + 4 * 65536);        // 2 KB
    u16* att = q;   // overlay q (dead after fattn)
    u16* y = k;     // overlay k (dead after merge)

    castw_kernel<<<dim3(64, 4), 256, 0, stream>>>(Wq, Wk, Wv, Wo, Wb, stats);
    tcast_kernel<<<dim3(LL / 64, CH / 64, NB), 256, 0, stream>>>(x, xT);
    projqk_kernel<<<dim3(LL / 64, 4, NB), 256, 0, stream>>>(xT, Wb, q, k);
    projv_kernel<<<dim3(LL / 128, CH / 64, NB), 256, 0, stream>>>(xT, Wb, vT);
    fattn_kernel<<<dim3(LL / 128, NB, S), 256, 0, stream>>>(q, k, vT, Op, l_s, iters);
    merge_kernel<<<(int)(elems / 8 / 256), 256, 0, stream>>>(Op, l_s, att, S);
    outm_kernel<<<dim3(LL / 128, CH / 64, NB), 256, 0, stream>>>(Wb, att, y, stats);
    bn_kernel<<<(NB * CH * LL / 4) / 256, 256, 0, stream>>>(x, y, stats, gamma, beta, out);
}

// Round 4
// 208.640 us; speedup vs baseline: 2.0147x; 1.2341x over previous
//
#include <hip/hip_runtime.h>
#include <cstdint>
#include <cstddef>

// Problem constants: N=4, C=D=256, H=W=64, L=4096
#define NB 4
#define CH 256
#define LL 4096

typedef unsigned short u16;
typedef unsigned int u32;
typedef unsigned char u8;
typedef __attribute__((ext_vector_type(8))) short bf16x8;
typedef __attribute__((ext_vector_type(4))) float f32x4;

#define GPTR(p) ((const __attribute__((address_space(1))) u32*)(p))
#define LPTR(p) ((__attribute__((address_space(3))) u32*)(p))

__device__ __forceinline__ float blo(u32 x) { return __uint_as_float(x << 16); }
__device__ __forceinline__ float bhi(u32 x) { return __uint_as_float(x & 0xffff0000u); }
__device__ __forceinline__ float b2f(u16 h) { return __uint_as_float(((u32)h) << 16); }
__device__ __forceinline__ u16 f2b(float f) {
    u32 u = __float_as_uint(f);
    u32 r = (u + 0x7fffu + ((u >> 16) & 1u)) >> 16;  // RNE
    return (u16)r;
}
__device__ __forceinline__ u32 pack2(float a, float b) {
    return (u32)f2b(a) | ((u32)f2b(b) << 16);
}

// ---------------------------------------------------------------------------
// Kernel 0b: cast weights to bf16 (Wb[mat][d][c]) + zero BN stats.
// ---------------------------------------------------------------------------
__global__ __launch_bounds__(256) void castw_kernel(
    const float* __restrict__ Wq, const float* __restrict__ Wk,
    const float* __restrict__ Wv, const float* __restrict__ Wo,
    u16* __restrict__ Wb, float* __restrict__ stats) {
    const int i = blockIdx.x * 256 + threadIdx.x;
    const int m = blockIdx.y;
    if (m == 0 && blockIdx.x < 2) stats[i] = 0.0f;
    const float* src = (m == 0) ? Wq : (m == 1) ? Wk : (m == 2) ? Wv : Wo;
    float4 v = ((const float4*)src)[i];
    uint2 o;
    o.x = pack2(v.x, v.y);
    o.y = pack2(v.z, v.w);
    ((uint2*)(Wb + m * 65536))[i] = o;
}

// ---------------------------------------------------------------------------
// Kernel 0c: transpose-cast x[n][c][l] f32 -> xT[n][l][c] bf16 (64x64 tiles).
// ---------------------------------------------------------------------------
__global__ __launch_bounds__(256) void tcast_kernel(
    const float* __restrict__ x, u16* __restrict__ xT) {
    const int n = blockIdx.z;
    const int c0 = blockIdx.y * 64, l0 = blockIdx.x * 64;
    __shared__ u16 t[64][72];
    const float* xs = x + (size_t)n * CH * LL;
    const int tid = threadIdx.x;
    const int lq = (tid & 15) * 4, cc = tid >> 4;
#pragma unroll
    for (int p = 0; p < 4; ++p) {
        int c = cc + p * 16;
        float4 v = *(const float4*)&xs[(size_t)(c0 + c) * LL + l0 + lq];
        t[lq + 0][c] = f2b(v.x);
        t[lq + 1][c] = f2b(v.y);
        t[lq + 2][c] = f2b(v.z);
        t[lq + 3][c] = f2b(v.w);
    }
    __syncthreads();
    u16* xo = xT + (size_t)n * LL * CH;
    const int l = tid >> 2, c8 = (tid & 3) * 16;
#pragma unroll
    for (int h = 0; h < 2; ++h) {
        uint4 vv = *(uint4*)&t[l][c8 + h * 8];
        *(uint4*)&xo[(size_t)(l0 + l) * CH + c0 + c8 + h * 8] = vv;
    }
}

// ---------------------------------------------------------------------------
// Kernel 1a: q/k projections via bf16 MFMA, output bf16. R14: B-operand
// (weights, 128x256 = 64 KB) STAGED IN LDS via global_load_lds + chunk-XOR
// swizzle (fattn's proven okK pattern). R2 measured the old per-MFMA global
// fragment read pattern at MfmaUtil ~11% (L2 latency exposed per operand);
// weights also exceed L1 (64 KB > 32 KB) and were re-read by all 4 waves.
// One barrier after staging; inner loop = swizzled ds_read_b128 + MFMA.
// ---------------------------------------------------------------------------
__global__ __launch_bounds__(256, 2) void projqk_kernel(
    const u16* __restrict__ xT, const u16* __restrict__ Wb,
    u16* __restrict__ q, u16* __restrict__ k) {
    const int n = blockIdx.z;
    const int dhalf = blockIdx.y & 1, mat = blockIdx.y >> 1;
    const int l0 = blockIdx.x * 64;
    const int d0 = dhalf * 128;
    const int tid = threadIdx.x;
    const int w = tid >> 6, lane = tid & 63;
    const int lhi = lane >> 4, llo = lane & 15;

    __shared__ __align__(16) u16 Bs[128 * 256];  // 64 KB, chunk-XOR swizzled

    const u16* xn = xT + (size_t)n * LL * CH;
    const u16* Wm = Wb + mat * 65536 + (size_t)d0 * CH;

    // stage B = Wm[0..128) x 256: LDS slot s=i*256+tid (linear dest), source
    // chunk pre-swizzled with c ^ (r&31) (self-inverse, bijective per row).
#pragma unroll
    for (int i = 0; i < 16; ++i) {
        int s = i * 256 + tid;
        int r = s >> 5, c = s & 31;
        __builtin_amdgcn_global_load_lds(GPTR(Wm + r * CH + (c ^ (r & 31)) * 8),
                                         LPTR((char*)Bs + i * 4096 + w * 1024),
                                         16, 0, 0);
    }

    bf16x8 af[8];
    const u16* abase = xn + (size_t)(l0 + w * 16 + llo) * CH + lhi * 8;
#pragma unroll
    for (int ks = 0; ks < 8; ++ks) af[ks] = *(const bf16x8*)(abase + ks * 32);

    f32x4 acc[8];
#pragma unroll
    for (int t = 0; t < 8; ++t) acc[t] = (f32x4){0.f, 0.f, 0.f, 0.f};

    __syncthreads();  // staging (and af) complete

#pragma unroll
    for (int ks = 0; ks < 8; ++ks) {
#pragma unroll
        for (int ct = 0; ct < 8; ++ct) {
            const int rr = ct * 16 + llo;
            bf16x8 bf = *(const bf16x8*)(Bs + rr * CH +
                                         ((ks * 4 + lhi) ^ (rr & 31)) * 8);
            acc[ct] = __builtin_amdgcn_mfma_f32_16x16x32_bf16(af[ks], bf, acc[ct], 0, 0, 0);
        }
    }

    u16* o = (mat ? k : q) + (size_t)n * LL * CH;
#pragma unroll
    for (int r = 0; r < 4; ++r) {
        int lr = l0 + w * 16 + lhi * 4 + r;
#pragma unroll
        for (int ct = 0; ct < 8; ++ct)
            o[(size_t)lr * CH + d0 + ct * 16 + llo] = f2b(acc[ct][r]);
    }
}

// ---------------------------------------------------------------------------
// Kernel 1b: v projection -> vT[n][d][l] bf16. A = Wv (regs), B = xT l-tile
// (128x256 = 64 KB) staged in LDS (R14, same swizzle template as projqk).
// ---------------------------------------------------------------------------
__global__ __launch_bounds__(256, 2) void projv_kernel(
    const u16* __restrict__ xT, const u16* __restrict__ Wb,
    u16* __restrict__ vT) {
    const int n = blockIdx.z;
    const int d0 = blockIdx.y * 64;
    const int l0 = blockIdx.x * 128;
    const int tid = threadIdx.x;
    const int w = tid >> 6, lane = tid & 63;
    const int lhi = lane >> 4, llo = lane & 15;

    __shared__ __align__(16) u16 Bs[128 * 256];  // 64 KB

    const u16* xn = xT + (size_t)n * LL * CH + (size_t)l0 * CH;
    const u16* Wm = Wb + 2 * 65536;

#pragma unroll
    for (int i = 0; i < 16; ++i) {
        int s = i * 256 + tid;
        int r = s >> 5, c = s & 31;
        __builtin_amdgcn_global_load_lds(GPTR(xn + r * CH + (c ^ (r & 31)) * 8),
                                         LPTR((char*)Bs + i * 4096 + w * 1024),
                                         16, 0, 0);
    }

    bf16x8 af[8];
    const u16* abase = Wm + (size_t)(d0 + w * 16 + llo) * CH + lhi * 8;
#pragma unroll
    for (int ks = 0; ks < 8; ++ks) af[ks] = *(const bf16x8*)(abase + ks * 32);

    f32x4 acc[8];
#pragma unroll
    for (int t = 0; t < 8; ++t) acc[t] = (f32x4){0.f, 0.f, 0.f, 0.f};

    __syncthreads();

#pragma unroll
    for (int ks = 0; ks < 8; ++ks) {
#pragma unroll
        for (int ct = 0; ct < 8; ++ct) {
            const int rr = ct * 16 + llo;
            bf16x8 bf = *(const bf16x8*)(Bs + rr * CH +
                                         ((ks * 4 + lhi) ^ (rr & 31)) * 8);
            acc[ct] = __builtin_amdgcn_mfma_f32_16x16x32_bf16(af[ks], bf, acc[ct], 0, 0, 0);
        }
    }

    u16* o = vT + (size_t)n * CH * LL;
#pragma unroll
    for (int r = 0; r < 4; ++r) {
        int dr = d0 + w * 16 + lhi * 4 + r;
#pragma unroll
        for (int ct = 0; ct < 8; ++ct)
            o[(size_t)dr * LL + l0 + ct * 16 + llo] = f2b(acc[ct][r]);
    }
}

// ---------------------------------------------------------------------------
// Kernel 2: bf16 flash attention (R13 structure, unchanged in R14 -- serves
// as the control: counters should repeat ~89 us / MfmaUtil ~31.6).
// Swapped QK^T (mfma(A=K,B=Q)) -> q-row lane-local P; in-register P via
// cvt_pk_bf16 + ds_bpermute; double-buffered K/V staging via global_load_lds.
// LDS 65536 B: K[2][32][256] | V[2][256][32] (chunk-XOR swizzles). 2 blk/CU.
// ---------------------------------------------------------------------------
__global__ __launch_bounds__(256, 2) void fattn_kernel(
    const u16* __restrict__ q, const u16* __restrict__ k,
    const u16* __restrict__ vT, u16* __restrict__ Op, float* __restrict__ l_s,
    int iters) {
    const int n = blockIdx.y;
    const int s_id = blockIdx.z;
    const int l0 = blockIdx.x * 128;
    const int m_base = s_id * iters * 32;
    const int tid = threadIdx.x;
    const int w = tid >> 6;
    const int lane = tid & 63;
    const int lhi = lane >> 4, llo = lane & 15;

    __shared__ __align__(16) char smem[65536];
    // K buffers @ 0 / 16384 ; V buffers @ 32768 / 49152

    bf16x8 qf[2][8];
    {
        const u16* base = q + (size_t)(n * LL + l0 + w * 32 + llo) * CH + lhi * 8;
#pragma unroll
        for (int t = 0; t < 2; ++t)
#pragma unroll
            for (int ks = 0; ks < 8; ++ks)
                qf[t][ks] = *(const bf16x8*)(base + t * 16 * CH + ks * 32);
    }

    const u16* kg = k + (size_t)n * LL * CH;
    const u16* vg = vT + (size_t)n * CH * LL;

    int okK[4], okV[4];
#pragma unroll
    for (int i = 0; i < 4; ++i) {
        int s = i * 256 + tid;
        int rK = s >> 5;
        int cK = (s & 31) ^ rK;
        okK[i] = rK * CH + cK * 8;
        int dV = s >> 2;
        int cV = (s & 3) ^ ((dV & 3) ^ ((dV >> 2) & 3));
        okV[i] = dV * LL + cV * 8;
    }

    f32x4 oacc[2][16];
#pragma unroll
    for (int t = 0; t < 2; ++t)
#pragma unroll
        for (int ct = 0; ct < 16; ++ct) oacc[t][ct] = (f32x4){0.f, 0.f, 0.f, 0.f};
    float lrun[2] = {0.f, 0.f};

    const float C1 = 0.09016844005556021f;  // (1/16) * log2(e)
    const int posV = (lhi ^ ((llo & 3) ^ (llo >> 2))) * 8;
    const int idxA = (llo + 32 * (lhi & 1)) * 4;
    const int idxB = idxA + 64;
    const bool selLo = (lhi < 2);

    {
        const u16* kg2 = kg + (size_t)m_base * CH;
        const u16* vg2 = vg + m_base;
#pragma unroll
        for (int i = 0; i < 4; ++i) {
            __builtin_amdgcn_global_load_lds(GPTR(kg2 + okK[i]),
                                             LPTR(smem + i * 4096 + w * 1024), 16, 0, 0);
            __builtin_amdgcn_global_load_lds(GPTR(vg2 + okV[i]),
                                             LPTR(smem + 32768 + i * 4096 + w * 1024),
                                             16, 0, 0);
        }
    }

    for (int it = 0; it < iters; ++it) {
        __syncthreads();
        if (it + 1 < iters) {
            const int m1 = m_base + (it + 1) * 32;
            const u16* kg2 = kg + (size_t)m1 * CH;
            const u16* vg2 = vg + m1;
            char* Kb = smem + ((it + 1) & 1) * 16384;
            char* Vb = smem + 32768 + ((it + 1) & 1) * 16384;
#pragma unroll
            for (int i = 0; i < 4; ++i) {
                __builtin_amdgcn_global_load_lds(GPTR(kg2 + okK[i]),
                                                 LPTR(Kb + i * 4096 + w * 1024), 16, 0, 0);
                __builtin_amdgcn_global_load_lds(GPTR(vg2 + okV[i]),
                                                 LPTR(Vb + i * 4096 + w * 1024), 16, 0, 0);
            }
        }
        const u16* Kl = (const u16*)(smem + (it & 1) * 16384);
        const u16* Vl = (const u16*)(smem + 32768 + (it & 1) * 16384);

        f32x4 s00 = (f32x4){0.f, 0.f, 0.f, 0.f};
        f32x4 s01 = (f32x4){0.f, 0.f, 0.f, 0.f};
        f32x4 s10 = (f32x4){0.f, 0.f, 0.f, 0.f};
        f32x4 s11 = (f32x4){0.f, 0.f, 0.f, 0.f};
#pragma unroll
        for (int ks = 0; ks < 8; ++ks) {
            const int cq = ks * 4 + lhi;
            bf16x8 b0 = *(const bf16x8*)(Kl + llo * 256 + (cq ^ llo) * 8);
            bf16x8 b1 = *(const bf16x8*)(Kl + (llo + 16) * 256 + (cq ^ (llo + 16)) * 8);
            s00 = __builtin_amdgcn_mfma_f32_16x16x32_bf16(b0, qf[0][ks], s00, 0, 0, 0);
            s10 = __builtin_amdgcn_mfma_f32_16x16x32_bf16(b0, qf[1][ks], s10, 0, 0, 0);
            s01 = __builtin_amdgcn_mfma_f32_16x16x32_bf16(b1, qf[0][ks], s01, 0, 0, 0);
            s11 = __builtin_amdgcn_mfma_f32_16x16x32_bf16(b1, qf[1][ks], s11, 0, 0, 0);
        }

        bf16x8 pa[2];
#pragma unroll
        for (int qt = 0; qt < 2; ++qt) {
            f32x4 sa = qt ? s10 : s00;   // kt = 0
            f32x4 sb = qt ? s11 : s01;   // kt = 1
            float pA0 = __builtin_amdgcn_exp2f(sa[0] * C1);
            float pA1 = __builtin_amdgcn_exp2f(sa[1] * C1);
            float pA2 = __builtin_amdgcn_exp2f(sa[2] * C1);
            float pA3 = __builtin_amdgcn_exp2f(sa[3] * C1);
            float pB0 = __builtin_amdgcn_exp2f(sb[0] * C1);
            float pB1 = __builtin_amdgcn_exp2f(sb[1] * C1);
            float pB2 = __builtin_amdgcn_exp2f(sb[2] * C1);
            float pB3 = __builtin_amdgcn_exp2f(sb[3] * C1);
            lrun[qt] += ((pA0 + pA1) + (pA2 + pA3)) + ((pB0 + pB1) + (pB2 + pB3));
            u32 w0, w1, w2, w3;
            asm("v_cvt_pk_bf16_f32 %0, %1, %2" : "=v"(w0) : "v"(pA0), "v"(pA1));
            asm("v_cvt_pk_bf16_f32 %0, %1, %2" : "=v"(w1) : "v"(pA2), "v"(pA3));
            asm("v_cvt_pk_bf16_f32 %0, %1, %2" : "=v"(w2) : "v"(pB0), "v"(pB1));
            asm("v_cvt_pk_bf16_f32 %0, %1, %2" : "=v"(w3) : "v"(pB2), "v"(pB3));
            int t0 = __builtin_amdgcn_ds_bpermute(idxA, (int)w0);
            int t2 = __builtin_amdgcn_ds_bpermute(idxA, (int)w2);
            int u0 = __builtin_amdgcn_ds_bpermute(idxA, (int)w1);
            int u2 = __builtin_amdgcn_ds_bpermute(idxA, (int)w3);
            int v0 = __builtin_amdgcn_ds_bpermute(idxB, (int)w0);
            int v2 = __builtin_amdgcn_ds_bpermute(idxB, (int)w2);
            int x0 = __builtin_amdgcn_ds_bpermute(idxB, (int)w1);
            int x2 = __builtin_amdgcn_ds_bpermute(idxB, (int)w3);
            union { u32 u[4]; bf16x8 v; } pk;
            pk.u[0] = selLo ? (u32)t0 : (u32)t2;
            pk.u[1] = selLo ? (u32)u0 : (u32)u2;
            pk.u[2] = selLo ? (u32)v0 : (u32)v2;
            pk.u[3] = selLo ? (u32)x0 : (u32)x2;
            pa[qt] = pk.v;
        }

#pragma unroll
        for (int ct = 0; ct < 16; ++ct) {
            bf16x8 vf = *(const bf16x8*)(Vl + (ct * 16 + llo) * 32 + posV);
            oacc[0][ct] = __builtin_amdgcn_mfma_f32_16x16x32_bf16(pa[0], vf, oacc[0][ct], 0, 0, 0);
            oacc[1][ct] = __builtin_amdgcn_mfma_f32_16x16x32_bf16(pa[1], vf, oacc[1][ct], 0, 0, 0);
        }
    }

    u16* ap = Op + (size_t)((s_id * NB + n) * (size_t)LL + l0 + w * 32) * CH;
    float* lp = l_s + (size_t)s_id * NB * LL + (size_t)n * LL + l0 + w * 32;
#pragma unroll
    for (int t = 0; t < 2; ++t) {
        float ls = lrun[t];
        ls += __shfl_xor(ls, 16);
        ls += __shfl_xor(ls, 32);
        if (lhi == 0) lp[t * 16 + llo] = ls;
#pragma unroll
        for (int r = 0; r < 4; ++r) {
            int lrow = t * 16 + lhi * 4 + r;
#pragma unroll
            for (int ct = 0; ct < 16; ++ct) {
                ap[(size_t)lrow * CH + ct * 16 + llo] = f2b(oacc[t][ct][r]);
            }
        }
    }
}

// ---------------------------------------------------------------------------
// Kernel 2c: merge splits: att[i] = (sum_s Op[s][i]) / (sum_s l_s[s][row])
// ---------------------------------------------------------------------------
__global__ __launch_bounds__(256) void merge_kernel(
    const u16* __restrict__ Op, const float* __restrict__ l_s,
    u16* __restrict__ att, int S) {
    const size_t t8 = (size_t)blockIdx.x * 256 + threadIdx.x;
    const size_t flat = t8 * 8;
    const size_t row = flat >> 8;
    float lsum = 0.0f;
    for (int s = 0; s < S; ++s) lsum += l_s[(size_t)s * NB * LL + row];
    const float inv = 1.0f / lsum;
    float acc[8];
#pragma unroll
    for (int j = 0; j < 8; ++j) acc[j] = 0.0f;
    for (int s = 0; s < S; ++s) {
        uint4 raw = *(const uint4*)(Op + (size_t)s * NB * LL * CH + flat);
        acc[0] += blo(raw.x); acc[1] += bhi(raw.x);
        acc[2] += blo(raw.y); acc[3] += bhi(raw.y);
        acc[4] += blo(raw.z); acc[5] += bhi(raw.z);
        acc[6] += blo(raw.w); acc[7] += bhi(raw.w);
    }
    uint4 o;
    o.x = pack2(acc[0] * inv, acc[1] * inv);
    o.y = pack2(acc[2] * inv, acc[3] * inv);
    o.z = pack2(acc[4] * inv, acc[5] * inv);
    o.w = pack2(acc[6] * inv, acc[7] * inv);
    *(uint4*)(att + flat) = o;
}

// ---------------------------------------------------------------------------
// Kernel 3: output projection via MFMA + fused BN partial sums. y bf16.
// R14: B = att l-tile staged in LDS (same template as projv).
// ---------------------------------------------------------------------------
__global__ __launch_bounds__(256, 2) void outm_kernel(
    const u16* __restrict__ Wb, const u16* __restrict__ att,
    u16* __restrict__ y, float* __restrict__ stats) {
    const int n = blockIdx.z;
    const int o0 = blockIdx.y * 64;
    const int l0 = blockIdx.x * 128;
    const int tid = threadIdx.x;
    const int w = tid >> 6, lane = tid & 63;
    const int lhi = lane >> 4, llo = lane & 15;

    __shared__ __align__(16) u16 Bs[128 * 256];  // 64 KB

    const u16* an = att + (size_t)n * LL * CH + (size_t)l0 * CH;
    const u16* Wm = Wb + 3 * 65536;

#pragma unroll
    for (int i = 0; i < 16; ++i) {
        int s = i * 256 + tid;
        int r = s >> 5, c = s & 31;
        __builtin_amdgcn_global_load_lds(GPTR(an + r * CH + (c ^ (r & 31)) * 8),
                                         LPTR((char*)Bs + i * 4096 + w * 1024),
                                         16, 0, 0);
    }

    bf16x8 af[8];
    const u16* abase = Wm + (size_t)(o0 + w * 16 + llo) * CH + lhi * 8;
#pragma unroll
    for (int ks = 0; ks < 8; ++ks) af[ks] = *(const bf16x8*)(abase + ks * 32);

    f32x4 acc[8];
#pragma unroll
    for (int t = 0; t < 8; ++t) acc[t] = (f32x4){0.f, 0.f, 0.f, 0.f};

    __syncthreads();

#pragma unroll
    for (int ks = 0; ks < 8; ++ks) {
#pragma unroll
        for (int ct = 0; ct < 8; ++ct) {
            const int rr = ct * 16 + llo;
            bf16x8 bf = *(const bf16x8*)(Bs + rr * CH +
                                         ((ks * 4 + lhi) ^ (rr & 31)) * 8);
            acc[ct] = __builtin_amdgcn_mfma_f32_16x16x32_bf16(af[ks], bf, acc[ct], 0, 0, 0);
        }
    }

    u16* yn = y + (size_t)n * CH * LL;
#pragma unroll
    for (int r = 0; r < 4; ++r) {
        const int orow = o0 + w * 16 + lhi * 4 + r;
        float ts = 0.0f, tq = 0.0f;
#pragma unroll
        for (int ct = 0; ct < 8; ++ct) {
            float vv = acc[ct][r];
            yn[(size_t)orow * LL + l0 + ct * 16 + llo] = f2b(vv);
            ts += vv;
            tq += vv * vv;
        }
        ts += __shfl_xor(ts, 1); tq += __shfl_xor(tq, 1);
        ts += __shfl_xor(ts, 2); tq += __shfl_xor(tq, 2);
        ts += __shfl_xor(ts, 4); tq += __shfl_xor(tq, 4);
        ts += __shfl_xor(ts, 8); tq += __shfl_xor(tq, 8);
        if (llo == 0) {
            atomicAdd(&stats[orow], ts);
            atomicAdd(&stats[256 + orow], tq);
        }
    }
}

// ---------------------------------------------------------------------------
// Kernel 4: BN apply (batch stats, biased var) + residual. y read as bf16.
// ---------------------------------------------------------------------------
__global__ __launch_bounds__(256) void bn_kernel(
    const float* __restrict__ x, const u16* __restrict__ y,
    const float* __restrict__ stats, const float* __restrict__ gamma,
    const float* __restrict__ beta, float* __restrict__ out) {
    const int idx = blockIdx.x * 256 + threadIdx.x;  // per 4 elems
    const int base = idx * 4;
    const int c = (base >> 12) & 255;  // (base / L) % C
    const float cnt = 1.0f / 16384.0f; // N*L
    float mean = stats[c] * cnt;
    float var = stats[256 + c] * cnt - mean * mean;
    float rstd = rsqrtf(var + 1e-4f);
    float g = gamma[c] * rstd;
    float b = beta[c];
    uint2 yv = ((const uint2*)y)[idx];
    float4 xv = ((const float4*)x)[idx];
    float4 o;
    o.x = xv.x + (blo(yv.x) - mean) * g + b;
    o.y = xv.y + (bhi(yv.x) - mean) * g + b;
    o.z = xv.z + (blo(yv.y) - mean) * g + b;
    o.w = xv.w + (bhi(yv.y) - mean) * g + b;
    ((float4*)out)[idx] = o;
}

// ---------------------------------------------------------------------------
extern "C" void kernel_launch(void* const* d_in, const int* in_sizes, int n_in,
                              void* d_out, int out_size, void* d_ws, size_t ws_size,
                              hipStream_t stream) {
    const float* x = (const float*)d_in[0];
    const float* Wq = (const float*)d_in[1];
    const float* Wk = (const float*)d_in[2];
    const float* Wv = (const float*)d_in[3];
    const float* Wo = (const float*)d_in[4];
    const float* gamma = (const float*)d_in[5];
    const float* beta = (const float*)d_in[6];
    float* out = (float*)d_out;

    const size_t elems = (size_t)NB * LL * CH;  // 4,194,304

    // pick largest split count whose workspace fits (S=4 needs ~59.4 MB)
    int S = 1;
    for (int cand = 4; cand >= 2; cand >>= 1) {
        size_t need = elems * 2 * (size_t)(3 + cand) +
                      (size_t)cand * NB * LL * 4 + 524288 + 8192;
        if (ws_size >= need) { S = cand; break; }
    }
    const int iters = 128 / S;

    char* wsb = (char*)d_ws;
    u16* q = (u16*)wsb;                             // 8.39 MB (bf16)
    u16* k = q + elems;                             // 8.39 MB (bf16)
    u16* vT = k + elems;                            // 8.39 MB (bf16)
    u16* Op = vT + elems;                           // S * 8.39 MB (bf16)
    u16* xT = Op;                                   // overlay: dead before fattn
    float* l_s = (float*)(Op + (size_t)S * elems);  // S * 64 KB
    u16* Wb = (u16*)(l_s + (size_t)S * NB * LL);    // 512 KB
    float* stats = (float*)(Wb + 4 * 65536);        // 2 KB
    u16* att = q;   // overlay q (dead after fattn)
    u16* y = k;     // overlay k (dead after merge)

    castw_kernel<<<dim3(64, 4), 256, 0, stream>>>(Wq, Wk, Wv, Wo, Wb, stats);
    tcast_kernel<<<dim3(LL / 64, CH / 64, NB), 256, 0, stream>>>(x, xT);
    projqk_kernel<<<dim3(LL / 64, 4, NB), 256, 0, stream>>>(xT, Wb, q, k);
    projv_kernel<<<dim3(LL / 128, CH / 64, NB), 256, 0, stream>>>(xT, Wb, vT);
    fattn_kernel<<<dim3(LL / 128, NB, S), 256, 0, stream>>>(q, k, vT, Op, l_s, iters);
    merge_kernel<<<(int)(elems / 8 / 256), 256, 0, stream>>>(Op, l_s, att, S);
    outm_kernel<<<dim3(LL / 128, CH / 64, NB), 256, 0, stream>>>(Wb, att, y, stats);
    bn_kernel<<<(NB * CH * LL / 4) / 256, 256, 0, stream>>>(x, y, stats, gamma, beta, out);
}